// Round 2
// baseline (1421.231 us; speedup 1.0000x reference)
//
#include <hip/hip_runtime.h>
#include <cstdint>
#include <cstddef>

// Problem constants (from reference: B=4, C=64, H=288, W=432, TEM=6)
#define NB 4
#define NC 64
#define HH 288
#define WW 432
#define PW 72                      // W / TEM
#define NV (HH*WW)                 // 124416 vertices
#define R_PER ((HH-1)*PW)          // 20664 row (vertical) edges per phase
#define C_PER (HH*(PW-1))          // 20448 col (horizontal) edges per phase
#define X_PER (HH*PW)              // 20736 cross edges per phase pair
#define PAIRW (R_PER + C_PER)      // 41112 weight-layout per-phase block
#define ROWS_TOT (6*R_PER)         // 123984
#define ROWCOL (6*PAIRW)           // 246672
#define NE (ROWCOL + 5*X_PER)      // 350352 edges
#define NTREE (NV-1)               // 124415
#define NROUNDS 18                 // >= ceil(log2 V)=17 guaranteed convergence
#define CHUNK 4096
#define NCHUNK ((NE + CHUNK - 1)/CHUNK)   // 86

typedef unsigned long long ull;

// ---- edge id -> endpoints, per the INDEX layout (rows ++ cols ++ cross) ----
__device__ __forceinline__ void index_uv(int e, int& u, int& v) {
    if (e < ROWS_TOT) {
        int t = e / R_PER, l = e - t * R_PER;
        int h = l / PW, x = l - h * PW;
        u = h * WW + t * PW + x; v = u + WW;
    } else if (e < ROWCOL) {
        int q = e - ROWS_TOT;
        int t = q / C_PER, l = q - t * C_PER;
        int h = l / (PW-1), x = l - h * (PW-1);
        u = h * WW + t * PW + x; v = u + 1;
    } else {
        int q = e - ROWCOL;
        int t = q / X_PER, l = q - t * X_PER;
        int h = l / PW, x = l - h * PW;
        u = h * WW + t * PW + x; v = u + PW;
    }
}

// ---- weight slot -> geometric endpoints, per the WEIGHT layout
// ([wr_t, wc_t] interleaved per phase, then cross) ----
__device__ __forceinline__ void weight_uv(int e, int& a, int& b) {
    if (e < ROWCOL) {
        int t = e / PAIRW, r = e - t * PAIRW;
        if (r < R_PER) {
            int h = r / PW, x = r - h * PW;
            a = h * WW + t * PW + x; b = a + WW;
        } else {
            int r2 = r - R_PER;
            int h = r2 / (PW-1), x = r2 - h * (PW-1);
            a = h * WW + t * PW + x; b = a + 1;
        }
    } else {
        int q = e - ROWCOL;
        int t = q / X_PER, l = q - t * X_PER;
        int h = l / PW, x = l - h * PW;
        a = h * WW + t * PW + x; b = a + PW;
    }
}

// root under parent forest; handles unbroken 2-cycles (mutual min edge) by
// rooting the smaller id — exactly the reference's (gp==idx)&(idx<parent) rule.
__device__ __forceinline__ int rootOf(const int* __restrict__ par, int c) {
    while (true) {
        int p = par[c];
        if (p == c) return c;
        int pp = par[p];
        if (pp == c) return c < p ? c : p;
        c = p;
    }
}

// wave-aggregated list append (order-free; consumers are order-independent)
__device__ __forceinline__ void wave_append(bool pred, int e, int* __restrict__ list,
                                            int* __restrict__ cnt) {
    ull m = __ballot(pred ? 1 : 0);
    if (m == 0) return;
    int lane = threadIdx.x & 63;
    int leader = __ffsll((long long)m) - 1;
    int base = 0;
    if (lane == leader) base = atomicAdd(cnt, __popcll(m));
    base = __shfl(base, leader);
    if (pred) list[base + __popcll(m & ((1ull << lane) - 1))] = e;
}

__global__ __launch_bounds__(256) void init_kernel(int* comp, int* parent,
                                                   ull* minkey, unsigned char* mask,
                                                   int* cntA, int* cntB) {
    int i = blockIdx.x * 256 + threadIdx.x;
    int b = blockIdx.y;
    if (i < NV) {
        comp[(size_t)b*NV + i] = i;
        parent[(size_t)b*NV + i] = i;
        minkey[(size_t)b*NV + i] = ~0ULL;
    }
    if (i < NE) mask[(size_t)b*NE + i] = 0;
    if (i == 0) { cntA[b] = 0; cntB[b] = 0; }
}

// key = (float_bits(w) << 32) | edge_id : strict total order == stable argsort rank
__global__ __launch_bounds__(256) void key_kernel(const float* __restrict__ fm,
                                                  ull* __restrict__ keys) {
    int e = blockIdx.x * 256 + threadIdx.x;
    int b = blockIdx.y;
    if (e >= NE) return;
    int a, c2;
    weight_uv(e, a, c2);
    const float* base = fm + (size_t)b * NC * NV;
    float w = 0.f;
    #pragma unroll 8
    for (int ch = 0; ch < NC; ++ch) {
        float d = base[(size_t)ch * NV + a] - base[(size_t)ch * NV + c2];
        w += d * d;
    }
    keys[(size_t)b * NE + e] =
        ((ull)__float_as_uint(w) << 32) | (unsigned int)e;
}

// Round 0 scan: all edges. Survivors (cross-component) appended to outList.
__global__ __launch_bounds__(256) void scan_full_kernel(const ull* __restrict__ keys,
                                                        int* __restrict__ comp,
                                                        const int* __restrict__ parent,
                                                        ull* __restrict__ minkey,
                                                        int* __restrict__ outList,
                                                        int* __restrict__ outCnt) {
    int e = blockIdx.x * 256 + threadIdx.x;
    int b = blockIdx.y;
    if (e >= NE) return;
    const int* par = parent + (size_t)b * NV;
    int* cmp = comp + (size_t)b * NV;
    int u, v;
    index_uv(e, u, v);
    int cu = rootOf(par, cmp[u]); cmp[u] = cu;  // benign race: all writers agree
    int cv = rootOf(par, cmp[v]); cmp[v] = cv;
    bool pred = (cu != cv);
    wave_append(pred, e, outList + (size_t)b * NE, &outCnt[b]);
    if (pred) {
        ull k = keys[(size_t)b * NE + e];
        ull* mk = minkey + (size_t)b * NV;
        if (k < mk[cu]) atomicMin(&mk[cu], k);  // pre-check kills hot-slot serialization
        if (k < mk[cv]) atomicMin(&mk[cv], k);
    }
}

// Rounds >= 1: scan only previous round's survivors.
__global__ __launch_bounds__(256) void scan_list_kernel(const ull* __restrict__ keys,
                                                        int* __restrict__ comp,
                                                        const int* __restrict__ parent,
                                                        ull* __restrict__ minkey,
                                                        const int* __restrict__ inList,
                                                        const int* __restrict__ inCnt,
                                                        int* __restrict__ outList,
                                                        int* __restrict__ outCnt) {
    int i = blockIdx.x * 256 + threadIdx.x;
    int b = blockIdx.y;
    if (i >= inCnt[b]) return;
    int e = inList[(size_t)b * NE + i];
    const int* par = parent + (size_t)b * NV;
    int* cmp = comp + (size_t)b * NV;
    int u, v;
    index_uv(e, u, v);
    int cu = rootOf(par, cmp[u]); cmp[u] = cu;
    int cv = rootOf(par, cmp[v]); cmp[v] = cv;
    bool pred = (cu != cv);
    wave_append(pred, e, outList + (size_t)b * NE, &outCnt[b]);
    if (pred) {
        ull k = keys[(size_t)b * NE + e];
        ull* mk = minkey + (size_t)b * NV;
        if (k < mk[cu]) atomicMin(&mk[cu], k);
        if (k < mk[cv]) atomicMin(&mk[cv], k);
    }
}

// Phase 2: per component, read winning edge, mark mask, hook parent, reset minkey.
// cntCons: input count the preceding scan consumed (reset for reuse 2 rounds later).
// cntProd: count the preceding scan produced; 0 => no atomics fired => minkey is
// still all-~0 and no hooks happened => whole pass is a no-op, skip it.
__global__ __launch_bounds__(256) void select_kernel(const int* __restrict__ comp,
                                                     int* __restrict__ parent,
                                                     ull* __restrict__ minkey,
                                                     unsigned char* __restrict__ mask,
                                                     const int* __restrict__ cntProd,
                                                     int* __restrict__ cntCons) {
    int c = blockIdx.x * 256 + threadIdx.x;
    int b = blockIdx.y;
    if (c == 0) cntCons[b] = 0;
    if (cntProd[b] == 0) return;   // converged batch: stale parent hooks are idempotent
    if (c >= NV) return;
    size_t off = (size_t)b * NV;
    ull k = minkey[off + c];
    minkey[off + c] = ~0ULL;                    // reset for next round
    int par = c;
    if (k != ~0ULL) {
        int e = (int)(k & 0xffffffffu);
        mask[(size_t)b * NE + e] = 1;           // idempotent
        int u, v;
        index_uv(e, u, v);
        int cu = comp[off + u], cv = comp[off + v];
        par = (cu == c) ? cv : cu;              // "other" component
    }
    parent[off + c] = par;
}

__global__ __launch_bounds__(256) void count_kernel(const unsigned char* __restrict__ mask,
                                                    int* __restrict__ counts) {
    int b = blockIdx.y, ck = blockIdx.x, t = threadIdx.x;
    const unsigned char* m = mask + (size_t)b * NE;
    int base_e = ck * CHUNK + t * 16;
    int cnt = 0;
    #pragma unroll
    for (int i = 0; i < 16; ++i) {
        int e = base_e + i;
        if (e < NE && m[e]) cnt++;
    }
    __shared__ int sh[256];
    sh[t] = cnt;
    __syncthreads();
    for (int o = 128; o > 0; o >>= 1) {
        if (t < o) sh[t] += sh[t + o];
        __syncthreads();
    }
    if (t == 0) counts[b * NCHUNK + ck] = sh[0];
}

__global__ void offs_kernel(const int* __restrict__ counts, int* __restrict__ offsets) {
    int b = threadIdx.x;
    if (b >= NB) return;
    int run = 0;
    for (int ck = 0; ck < NCHUNK; ++ck) {
        int c = counts[b * NCHUNK + ck];
        offsets[b * NCHUNK + ck] = run;
        run += c;
    }
}

__global__ __launch_bounds__(256) void write_kernel(const unsigned char* __restrict__ mask,
                                                    const int* __restrict__ offsets,
                                                    int* __restrict__ out) {
    int b = blockIdx.y, ck = blockIdx.x, t = threadIdx.x;
    const unsigned char* m = mask + (size_t)b * NE;
    int base_e = ck * CHUNK + t * 16;
    int cnt = 0;
    #pragma unroll
    for (int i = 0; i < 16; ++i) {
        int e = base_e + i;
        if (e < NE && m[e]) cnt++;
    }
    __shared__ int sh[256];
    sh[t] = cnt;
    __syncthreads();
    // Hillis-Steele inclusive scan over 256 thread counts
    for (int o = 1; o < 256; o <<= 1) {
        int v = 0;
        if (t >= o) v = sh[t - o];
        __syncthreads();
        sh[t] += v;
        __syncthreads();
    }
    int pos = offsets[b * NCHUNK + ck] + (sh[t] - cnt);
    for (int i = 0; i < 16; ++i) {
        int e = base_e + i;
        if (e < NE && m[e]) {
            if (pos < NTREE) out[(size_t)b * NTREE + pos] = e;
            pos++;
        }
    }
}

extern "C" void kernel_launch(void* const* d_in, const int* in_sizes, int n_in,
                              void* d_out, int out_size, void* d_ws, size_t ws_size,
                              hipStream_t stream) {
    const float* fm = (const float*)d_in[0];
    int* out = (int*)d_out;   // reference output dtype is int32

    char* ws = (char*)d_ws;
    size_t off = 0;
    auto alloc = [&](size_t bytes) -> void* {
        void* p = ws + off;
        off += (bytes + 255) & ~(size_t)255;
        return p;
    };
    ull* keys    = (ull*)alloc((size_t)NB * NE * 8);
    ull* minkey  = (ull*)alloc((size_t)NB * NV * 8);
    int* comp    = (int*)alloc((size_t)NB * NV * 4);
    int* parent  = (int*)alloc((size_t)NB * NV * 4);
    unsigned char* mask = (unsigned char*)alloc((size_t)NB * NE);
    int* counts  = (int*)alloc((size_t)NB * NCHUNK * 4);
    int* offsets = (int*)alloc((size_t)NB * NCHUNK * 4);
    int* listA   = (int*)alloc((size_t)NB * NE * 4);
    int* listB   = (int*)alloc((size_t)NB * NE * 4);
    int* cntA    = (int*)alloc(NB * 4);
    int* cntB    = (int*)alloc(NB * 4);
    int* dummy   = (int*)alloc(NB * 4);

    dim3 blk(256);
    dim3 gE((NE + 255) / 256, NB);
    dim3 gV((NV + 255) / 256, NB);

    init_kernel<<<gE, blk, 0, stream>>>(comp, parent, minkey, mask, cntA, cntB);
    key_kernel<<<gE, blk, 0, stream>>>(fm, keys);

    // Round 0: full edge scan, survivors -> listB/cntB
    scan_full_kernel<<<gE, blk, 0, stream>>>(keys, comp, parent, minkey, listB, cntB);
    select_kernel<<<gV, blk, 0, stream>>>(comp, parent, minkey, mask, cntB, dummy);

    // Rounds 1..17: scan survivors only, ping-pong lists
    for (int r = 1; r < NROUNDS; ++r) {
        int* inL  = (r & 1) ? listB : listA;
        int* inC  = (r & 1) ? cntB  : cntA;
        int* outL = (r & 1) ? listA : listB;
        int* outC = (r & 1) ? cntA  : cntB;
        scan_list_kernel<<<gE, blk, 0, stream>>>(keys, comp, parent, minkey,
                                                 inL, inC, outL, outC);
        select_kernel<<<gV, blk, 0, stream>>>(comp, parent, minkey, mask, outC, inC);
    }

    count_kernel<<<dim3(NCHUNK, NB), blk, 0, stream>>>(mask, counts);
    offs_kernel<<<1, NB, 0, stream>>>(counts, offsets);
    write_kernel<<<dim3(NCHUNK, NB), blk, 0, stream>>>(mask, offsets, out);
}

// Round 3
// 667.443 us; speedup vs baseline: 2.1294x; 2.1294x over previous
//
#include <hip/hip_runtime.h>
#include <cstdint>
#include <cstddef>

// Problem constants (from reference: B=4, C=64, H=288, W=432, TEM=6)
#define NB 4
#define NC 64
#define HH 288
#define WW 432
#define PW 72                      // W / TEM
#define NV (HH*WW)                 // 124416 vertices
#define R_PER ((HH-1)*PW)          // 20664 row (vertical) edges per phase
#define C_PER (HH*(PW-1))          // 20448 col (horizontal) edges per phase
#define X_PER (HH*PW)              // 20736 cross edges per phase pair
#define PAIRW (R_PER + C_PER)      // 41112 weight-layout per-phase block
#define ROWS_TOT (6*R_PER)         // 123984
#define ROWCOL (6*PAIRW)           // 246672
#define NE (ROWCOL + 5*X_PER)      // 350352 edges
#define NTREE (NV-1)               // 124415
#define NROUNDS 18                 // >= ceil(log2 V)=17 guaranteed convergence
#define CHUNK 4096
#define NCHUNK ((NE + CHUNK - 1)/CHUNK)   // 86

typedef unsigned long long ull;

// ---- edge id -> endpoints, per the INDEX layout (rows ++ cols ++ cross) ----
__device__ __forceinline__ void index_uv(int e, int& u, int& v) {
    if (e < ROWS_TOT) {
        int t = e / R_PER, l = e - t * R_PER;
        int h = l / PW, x = l - h * PW;
        u = h * WW + t * PW + x; v = u + WW;
    } else if (e < ROWCOL) {
        int q = e - ROWS_TOT;
        int t = q / C_PER, l = q - t * C_PER;
        int h = l / (PW-1), x = l - h * (PW-1);
        u = h * WW + t * PW + x; v = u + 1;
    } else {
        int q = e - ROWCOL;
        int t = q / X_PER, l = q - t * X_PER;
        int h = l / PW, x = l - h * PW;
        u = h * WW + t * PW + x; v = u + PW;
    }
}

// ---- weight slot -> geometric endpoints, per the WEIGHT layout
// ([wr_t, wc_t] interleaved per phase, then cross) ----
__device__ __forceinline__ void weight_uv(int e, int& a, int& b) {
    if (e < ROWCOL) {
        int t = e / PAIRW, r = e - t * PAIRW;
        if (r < R_PER) {
            int h = r / PW, x = r - h * PW;
            a = h * WW + t * PW + x; b = a + WW;
        } else {
            int r2 = r - R_PER;
            int h = r2 / (PW-1), x = r2 - h * (PW-1);
            a = h * WW + t * PW + x; b = a + 1;
        }
    } else {
        int q = e - ROWCOL;
        int t = q / X_PER, l = q - t * X_PER;
        int h = l / PW, x = l - h * PW;
        a = h * WW + t * PW + x; b = a + PW;
    }
}

// root under parent forest; handles unbroken 2-cycles (mutual min edge) by
// rooting the smaller id — exactly the reference's (gp==idx)&(idx<parent) rule.
__device__ __forceinline__ int rootOf(const int* __restrict__ par, int c) {
    while (true) {
        int p = par[c];
        if (p == c) return c;
        int pp = par[p];
        if (pp == c) return c < p ? c : p;
        c = p;
    }
}

__global__ __launch_bounds__(256) void init_kernel(int* comp, int* parent,
                                                   ull* minkey, unsigned char* mask,
                                                   unsigned char* alive,
                                                   int* foundA, int* foundB, int* done) {
    int i = blockIdx.x * 256 + threadIdx.x;
    int b = blockIdx.y;
    if (i < NV) {
        comp[(size_t)b*NV + i] = i;
        parent[(size_t)b*NV + i] = i;
        minkey[(size_t)b*NV + i] = ~0ULL;
    }
    if (i < NE) {
        mask[(size_t)b*NE + i] = 0;
        alive[(size_t)b*NE + i] = 1;
    }
    if (i == 0) { foundA[b] = 0; foundB[b] = 0; done[b] = 0; }
}

// key = (float_bits(w) << 32) | edge_id : strict total order == stable argsort rank
__global__ __launch_bounds__(256) void key_kernel(const float* __restrict__ fm,
                                                  ull* __restrict__ keys) {
    int e = blockIdx.x * 256 + threadIdx.x;
    int b = blockIdx.y;
    if (e >= NE) return;
    int a, c2;
    weight_uv(e, a, c2);
    const float* base = fm + (size_t)b * NC * NV;
    float w = 0.f;
    #pragma unroll 8
    for (int ch = 0; ch < NC; ++ch) {
        float d = base[(size_t)ch * NV + a] - base[(size_t)ch * NV + c2];
        w += d * d;
    }
    keys[(size_t)b * NE + e] =
        ((ull)__float_as_uint(w) << 32) | (unsigned int)e;
}

// One Borůvka scan: coalesced over all edges; dead edges exit on a 1-byte read.
// foundCur[b]=1 (one store per wave) marks that this round has survivors.
__global__ __launch_bounds__(256) void scan_kernel(const ull* __restrict__ keys,
                                                   int* __restrict__ comp,
                                                   const int* __restrict__ parent,
                                                   ull* __restrict__ minkey,
                                                   unsigned char* __restrict__ alive,
                                                   int* __restrict__ foundCur,
                                                   const int* __restrict__ done) {
    int e = blockIdx.x * 256 + threadIdx.x;
    int b = blockIdx.y;
    if (e >= NE) return;
    if (done[b]) return;                         // converged: scalar read + exit
    if (!alive[(size_t)b * NE + e]) return;      // dead edge: 1B coalesced read
    const int* par = parent + (size_t)b * NV;
    int* cmp = comp + (size_t)b * NV;
    int u, v;
    index_uv(e, u, v);
    int cu = rootOf(par, cmp[u]);
    if (cmp[u] != cu) cmp[u] = cu;               // benign race: all writers agree
    int cv = rootOf(par, cmp[v]);
    if (cmp[v] != cv) cmp[v] = cv;
    bool pred = (cu != cv);
    if (!pred) alive[(size_t)b * NE + e] = 0;    // permanently intra-component
    ull m = __ballot(pred ? 1 : 0);
    if (m && (threadIdx.x & 63) == (unsigned)(__ffsll((long long)m) - 1))
        foundCur[b] = 1;                         // one store per wave
    if (pred) {
        ull k = keys[(size_t)b * NE + e];
        ull* mk = minkey + (size_t)b * NV;
        if (k < mk[cu]) atomicMin(&mk[cu], k);   // pre-check kills hot-slot serialization
        if (k < mk[cv]) atomicMin(&mk[cv], k);
    }
}

// Phase 2: per component, read winning edge, mark mask, hook parent, reset minkey.
// If the scan found no survivors, minkey is untouched (all ~0) and hooks would be
// idempotent: set done and skip. foundNext is reset for the round after next.
__global__ __launch_bounds__(256) void select_kernel(const int* __restrict__ comp,
                                                     int* __restrict__ parent,
                                                     ull* __restrict__ minkey,
                                                     unsigned char* __restrict__ mask,
                                                     const int* __restrict__ foundCur,
                                                     int* __restrict__ foundNext,
                                                     int* __restrict__ done) {
    int c = blockIdx.x * 256 + threadIdx.x;
    int b = blockIdx.y;
    int fc = foundCur[b];
    if (c == 0) {
        foundNext[b] = 0;
        if (fc == 0) done[b] = 1;                // monotone; visible to later scans
    }
    if (fc == 0) return;
    if (c >= NV) return;
    size_t off = (size_t)b * NV;
    ull k = minkey[off + c];
    int par = c;
    if (k != ~0ULL) {
        minkey[off + c] = ~0ULL;                 // reset only touched slots
        int e = (int)(k & 0xffffffffu);
        mask[(size_t)b * NE + e] = 1;            // idempotent
        int u, v;
        index_uv(e, u, v);
        int cu = comp[off + u], cv = comp[off + v];
        par = (cu == c) ? cv : cu;               // "other" component
    }
    if (parent[off + c] != par) parent[off + c] = par;
}

__global__ __launch_bounds__(256) void count_kernel(const unsigned char* __restrict__ mask,
                                                    int* __restrict__ counts) {
    int b = blockIdx.y, ck = blockIdx.x, t = threadIdx.x;
    const unsigned char* m = mask + (size_t)b * NE;
    int base_e = ck * CHUNK + t * 16;
    int cnt = 0;
    #pragma unroll
    for (int i = 0; i < 16; ++i) {
        int e = base_e + i;
        if (e < NE && m[e]) cnt++;
    }
    __shared__ int sh[256];
    sh[t] = cnt;
    __syncthreads();
    for (int o = 128; o > 0; o >>= 1) {
        if (t < o) sh[t] += sh[t + o];
        __syncthreads();
    }
    if (t == 0) counts[b * NCHUNK + ck] = sh[0];
}

__global__ void offs_kernel(const int* __restrict__ counts, int* __restrict__ offsets) {
    int b = threadIdx.x;
    if (b >= NB) return;
    int run = 0;
    for (int ck = 0; ck < NCHUNK; ++ck) {
        int c = counts[b * NCHUNK + ck];
        offsets[b * NCHUNK + ck] = run;
        run += c;
    }
}

__global__ __launch_bounds__(256) void write_kernel(const unsigned char* __restrict__ mask,
                                                    const int* __restrict__ offsets,
                                                    int* __restrict__ out) {
    int b = blockIdx.y, ck = blockIdx.x, t = threadIdx.x;
    const unsigned char* m = mask + (size_t)b * NE;
    int base_e = ck * CHUNK + t * 16;
    int cnt = 0;
    #pragma unroll
    for (int i = 0; i < 16; ++i) {
        int e = base_e + i;
        if (e < NE && m[e]) cnt++;
    }
    __shared__ int sh[256];
    sh[t] = cnt;
    __syncthreads();
    // Hillis-Steele inclusive scan over 256 thread counts
    for (int o = 1; o < 256; o <<= 1) {
        int v = 0;
        if (t >= o) v = sh[t - o];
        __syncthreads();
        sh[t] += v;
        __syncthreads();
    }
    int pos = offsets[b * NCHUNK + ck] + (sh[t] - cnt);
    for (int i = 0; i < 16; ++i) {
        int e = base_e + i;
        if (e < NE && m[e]) {
            if (pos < NTREE) out[(size_t)b * NTREE + pos] = e;
            pos++;
        }
    }
}

extern "C" void kernel_launch(void* const* d_in, const int* in_sizes, int n_in,
                              void* d_out, int out_size, void* d_ws, size_t ws_size,
                              hipStream_t stream) {
    const float* fm = (const float*)d_in[0];
    int* out = (int*)d_out;   // reference output dtype is int32

    char* ws = (char*)d_ws;
    size_t off = 0;
    auto alloc = [&](size_t bytes) -> void* {
        void* p = ws + off;
        off += (bytes + 255) & ~(size_t)255;
        return p;
    };
    ull* keys    = (ull*)alloc((size_t)NB * NE * 8);
    ull* minkey  = (ull*)alloc((size_t)NB * NV * 8);
    int* comp    = (int*)alloc((size_t)NB * NV * 4);
    int* parent  = (int*)alloc((size_t)NB * NV * 4);
    unsigned char* mask  = (unsigned char*)alloc((size_t)NB * NE);
    unsigned char* alive = (unsigned char*)alloc((size_t)NB * NE);
    int* counts  = (int*)alloc((size_t)NB * NCHUNK * 4);
    int* offsets = (int*)alloc((size_t)NB * NCHUNK * 4);
    int* foundA  = (int*)alloc(NB * 4);
    int* foundB  = (int*)alloc(NB * 4);
    int* done    = (int*)alloc(NB * 4);

    dim3 blk(256);
    dim3 gE((NE + 255) / 256, NB);
    dim3 gV((NV + 255) / 256, NB);

    init_kernel<<<gE, blk, 0, stream>>>(comp, parent, minkey, mask, alive,
                                        foundA, foundB, done);
    key_kernel<<<gE, blk, 0, stream>>>(fm, keys);

    for (int r = 0; r < NROUNDS; ++r) {
        int* fCur  = (r & 1) ? foundB : foundA;
        int* fNext = (r & 1) ? foundA : foundB;
        scan_kernel<<<gE, blk, 0, stream>>>(keys, comp, parent, minkey, alive,
                                            fCur, done);
        select_kernel<<<gV, blk, 0, stream>>>(comp, parent, minkey, mask,
                                              fCur, fNext, done);
    }

    count_kernel<<<dim3(NCHUNK, NB), blk, 0, stream>>>(mask, counts);
    offs_kernel<<<1, NB, 0, stream>>>(counts, offsets);
    write_kernel<<<dim3(NCHUNK, NB), blk, 0, stream>>>(mask, offsets, out);
}